// Round 1
// baseline (220.878 us; speedup 1.0000x reference)
//
#include <hip/hip_runtime.h>

#define TAGS 256

// One 64-lane wave per row of 256 tags. Lane i owns tags [4i, 4i+4).
// float4 load -> local argmax -> 6-step shfl_xor butterfly (val, idx) ->
// float4 gather of transitions[idx] -> add -> float4 store.
__global__ __launch_bounds__(256) void crf_head_kernel(
    const float* __restrict__ in,
    const float* __restrict__ trans,
    float* __restrict__ out,
    int rows)
{
    int gwave = (int)((blockIdx.x * blockDim.x + threadIdx.x) >> 6);
    int lane  = threadIdx.x & 63;
    if (gwave >= rows) return;

    const float4* row4 = (const float4*)(in + (size_t)gwave * TAGS);
    float4 v = row4[lane];

    // local argmax over 4 elements; strict > keeps the earliest index on ties
    float m  = v.x;
    int   mi = lane * 4;
    if (v.y > m) { m = v.y; mi = lane * 4 + 1; }
    if (v.z > m) { m = v.z; mi = lane * 4 + 2; }
    if (v.w > m) { m = v.w; mi = lane * 4 + 3; }

    // 64-lane butterfly; tie-break toward the smaller index (first occurrence)
    #pragma unroll
    for (int off = 32; off >= 1; off >>= 1) {
        float om  = __shfl_xor(m, off, 64);
        int   omi = __shfl_xor(mi, off, 64);
        if (om > m || (om == m && omi < mi)) { m = om; mi = omi; }
    }

    // gather the transitions row (hot in L1/L2: only 256 distinct rows)
    const float4* trow4 = (const float4*)(trans + (size_t)mi * TAGS);
    float4 t = trow4[lane];

    float4 o;
    o.x = v.x + t.x;
    o.y = v.y + t.y;
    o.z = v.z + t.z;
    o.w = v.w + t.w;
    ((float4*)(out + (size_t)gwave * TAGS))[lane] = o;
}

extern "C" void kernel_launch(void* const* d_in, const int* in_sizes, int n_in,
                              void* d_out, int out_size, void* d_ws, size_t ws_size,
                              hipStream_t stream) {
    const float* in    = (const float*)d_in[0];   // [B, T, TAGS] fp32
    const float* trans = (const float*)d_in[1];   // [TAGS, TAGS] fp32
    float* out = (float*)d_out;                   // [B, T, TAGS] fp32

    int rows = in_sizes[0] / TAGS;                // B*T = 131072
    // 4 waves (rows) per 256-thread block
    int blocks = (rows + 3) / 4;
    crf_head_kernel<<<dim3(blocks), dim3(256), 0, stream>>>(in, trans, out, rows);
}